// Round 12
// baseline (520.713 us; speedup 1.0000x reference)
//
#include <hip/hip_runtime.h>
#include <hip/hip_bf16.h>
#include <stdint.h>

#define NN 100000
#define NE 3200000
#define NPAD 100096   // 782*128
#define NB 391        // ceil(NN/256) buckets of 256 nodes
#define CAPB 12288    // per-bucket binned capacity
#define SCAP 9216     // per-bucket max real edges
#define GBLK 196      // k_group blocks
#define EPB 16384     // edges per k_group block

typedef float  f32x4 __attribute__((ext_vector_type(4)));
typedef short  bf16x8 __attribute__((ext_vector_type(8)));
typedef int    i32x4 __attribute__((ext_vector_type(4)));

__device__ __forceinline__ unsigned short f2bf(float f){
  __hip_bfloat16 b = __float2bfloat16(f);
  return __builtin_bit_cast(unsigned short, b);
}

// ---- fused prep: blocks 0..255 build WvT (swizzled bf16); blocks 256..511
// compute vq/vk rows; block 256 also computes consts. ----
__global__ __launch_bounds__(256) void k_prep(const float* __restrict__ Wv,
    const float* __restrict__ bv, const float* __restrict__ wq, const float* __restrict__ bq,
    const float* __restrict__ wk, const float* __restrict__ bk,
    unsigned short* __restrict__ wvt, float* __restrict__ vq, float* __restrict__ vk,
    float* __restrict__ consts){
  __shared__ float red[8];
  __shared__ float red2[8];
  if (blockIdx.x < 256){
    int n = blockIdx.x;
    int kp = threadIdx.x;
    int seg = kp >> 6, ct = (kp >> 3) & 7, o = kp & 7;
    int ks = (seg << 6) | ((ct ^ (n & 7)) << 3) | o;
    wvt[n * 256 + kp] = f2bf(Wv[ks * 256 + n]);
    return;
  }
  int k = blockIdx.x - 256, n = threadIdx.x;
  int wid = n >> 6, lane = n & 63;
  float w = Wv[k * 256 + n];
  float s1 = w * wq[n], s2 = w * wk[n];
  #pragma unroll
  for (int o = 32; o; o >>= 1){ s1 += __shfl_xor(s1, o, 64); s2 += __shfl_xor(s2, o, 64); }
  if (lane == 0){ red[wid] = s1; red[4 + wid] = s2; }
  __syncthreads();
  if (n == 0){ vq[k] = red[0]+red[1]+red[2]+red[3]; vk[k] = red[4]+red[5]+red[6]+red[7]; }
  if (k == 0){
    float t1 = bv[n] * wq[n], t2 = bv[n] * wk[n];
    #pragma unroll
    for (int o = 32; o; o >>= 1){ t1 += __shfl_xor(t1, o, 64); t2 += __shfl_xor(t2, o, 64); }
    if (lane == 0){ red2[wid] = t1; red2[4 + wid] = t2; }
    __syncthreads();
    if (n == 0){
      consts[0] = red2[0]+red2[1]+red2[2]+red2[3] + bq[0];
      consts[1] = red2[4]+red2[5]+red2[6]+red2[7] + bk[0];
    }
  }
}

// ---- fused: x -> bf16 (swizzled) AND q,k per node. One wave per row. ----
__global__ __launch_bounds__(256) void k_convert_qk(const float* __restrict__ x,
    const float* __restrict__ vq, const float* __restrict__ vk, const float* __restrict__ consts,
    unsigned short* __restrict__ xs, float* __restrict__ q, float* __restrict__ kv){
  int row = (blockIdx.x * 256 + threadIdx.x) >> 6;
  int lane = threadIdx.x & 63;
  f32x4 xv = *(const f32x4*)(x + (size_t)row * 256 + lane * 4);
  f32x4 a  = *(const f32x4*)(vq + lane * 4);
  f32x4 b  = *(const f32x4*)(vk + lane * 4);
  float s1 = xv[0]*a[0] + xv[1]*a[1] + xv[2]*a[2] + xv[3]*a[3];
  float s2 = xv[0]*b[0] + xv[1]*b[1] + xv[2]*b[2] + xv[3]*b[3];
  ushort4 v4;
  v4.x = f2bf(xv[0]); v4.y = f2bf(xv[1]); v4.z = f2bf(xv[2]); v4.w = f2bf(xv[3]);
  int ct = ((lane >> 1) & 7) ^ (row & 7);
  char* dst = (char*)xs + (size_t)row * 512 + (lane >> 4) * 128 + ct * 16 + (lane & 1) * 8;
  *(ushort4*)dst = v4;
  #pragma unroll
  for (int o = 32; o; o >>= 1){ s1 += __shfl_xor(s1, o, 64); s2 += __shfl_xor(s2, o, 64); }
  if (lane == 0){ q[row] = s1 + consts[0]; kv[row] = s2 + consts[1]; }
}

// ---- h = bf16(x@Wv + bv), 128x128 tile, BK=64, MFMA 16x16x32; h[N][256] ----
__global__ __launch_bounds__(256) void k_gemm(const unsigned short* __restrict__ xs,
    const unsigned short* __restrict__ wvt, const float* __restrict__ bv,
    unsigned short* __restrict__ h){
  __shared__ unsigned short As[128 * 64];
  __shared__ unsigned short Bs[128 * 64];
  int bid = blockIdx.x;
  int bm = bid >> 1, bn = bid & 1;
  int tid = threadIdx.x, wid = tid >> 6, lane = tid & 63;
  int wr = wid >> 1, wc = wid & 1;
  f32x4 zero = {0.f, 0.f, 0.f, 0.f};
  f32x4 acc[4][4];
  #pragma unroll
  for (int i = 0; i < 4; i++)
    #pragma unroll
    for (int j = 0; j < 4; j++) acc[i][j] = zero;
  const char* gA0 = (const char*)xs  + (size_t)bm * 128 * 512;
  const char* gB0 = (const char*)wvt + (size_t)bn * 128 * 512;
  for (int k0b = 0; k0b < 512; k0b += 128){
    #pragma unroll
    for (int it = 0; it < 4; ++it){
      int base = (wid * 4 + it) * 1024;
      int loff = base + lane * 16;
      int row = loff >> 7, cb = loff & 127;
      __builtin_amdgcn_global_load_lds(
        (const __attribute__((address_space(1))) void*)(gA0 + (size_t)row * 512 + k0b + cb),
        (__attribute__((address_space(3))) void*)((char*)As + base), 16, 0, 0);
      __builtin_amdgcn_global_load_lds(
        (const __attribute__((address_space(1))) void*)(gB0 + (size_t)row * 512 + k0b + cb),
        (__attribute__((address_space(3))) void*)((char*)Bs + base), 16, 0, 0);
    }
    __syncthreads();
    #pragma unroll
    for (int kk = 0; kk < 2; ++kk){
      bf16x8 af[4], bfr[4];
      int cbase = kk * 4 + (lane >> 4);
      #pragma unroll
      for (int m = 0; m < 4; m++){
        int row = wr * 64 + m * 16 + (lane & 15);
        int c = cbase ^ (row & 7);
        af[m] = *(const bf16x8*)(As + row * 64 + c * 8);
      }
      #pragma unroll
      for (int n = 0; n < 4; n++){
        int col = wc * 64 + n * 16 + (lane & 15);
        int c = cbase ^ (col & 7);
        bfr[n] = *(const bf16x8*)(Bs + col * 64 + c * 8);
      }
      #pragma unroll
      for (int m = 0; m < 4; m++)
        #pragma unroll
        for (int n = 0; n < 4; n++)
          acc[m][n] = __builtin_amdgcn_mfma_f32_16x16x32_bf16(af[m], bfr[n], acc[m][n], 0, 0, 0);
    }
    __syncthreads();
  }
  int colb = bn * 128 + wc * 64;
  float bvv[4];
  #pragma unroll
  for (int n = 0; n < 4; n++) bvv[n] = bv[colb + n * 16 + (lane & 15)];
  #pragma unroll
  for (int m = 0; m < 4; m++){
    int rowb = bm * 128 + wr * 64 + m * 16 + (lane >> 4) * 4;
    #pragma unroll
    for (int n = 0; n < 4; n++){
      int col = colb + n * 16 + (lane & 15);
      #pragma unroll
      for (int i = 0; i < 4; i++)
        h[(size_t)(rowb + i) * 256 + col] = f2bf(acc[m][n][i] + bvv[n]);
    }
  }
}

// ---- Phase A: stage 16K edges in LDS, group by bucket (d>>8), write
// 16-aligned sentinel-padded spans to binned[bkt*CAPB + reserved]. ----
__global__ __launch_bounds__(256) void k_group(const int* __restrict__ src,
    const int* __restrict__ dst, int* __restrict__ gTail, int* __restrict__ gReal,
    unsigned int* __restrict__ binned){
  __shared__ unsigned int   raw[EPB];    // 64 KB: packed (s<<8)|(d&255)
  __shared__ unsigned short rawB[EPB];   // 32 KB: bucket id (0xFFFF = invalid)
  __shared__ int cnt[NB];
  __shared__ int base[NB];
  __shared__ int cnt2[NB];
  int tid = threadIdx.x;
  for (int b = tid; b < NB; b += 256){ cnt[b] = 0; cnt2[b] = 0; }
  __syncthreads();
  int e0 = blockIdx.x * EPB;
  for (int r = 0; r < 16; ++r){
    int ebase = e0 + r * 1024 + tid * 4;
    int slot  = r * 1024 + tid * 4;
    uint4 vv; ushort4 bb4;
    if (ebase + 3 < NE){
      i32x4 s4 = __builtin_nontemporal_load((const i32x4*)(src + ebase));
      i32x4 d4 = __builtin_nontemporal_load((const i32x4*)(dst + ebase));
      #pragma unroll
      for (int j = 0; j < 4; j++){
        int d = d4[j]; int bkt = d >> 8;
        ((unsigned int*)&vv)[j] = ((unsigned)s4[j] << 8) | (unsigned)(d & 255);
        ((unsigned short*)&bb4)[j] = (unsigned short)bkt;
        atomicAdd(&cnt[bkt], 1);
      }
    } else {
      #pragma unroll
      for (int j = 0; j < 4; j++){
        int e = ebase + j;
        if (e < NE){
          int d = dst[e]; int s = src[e]; int bkt = d >> 8;
          ((unsigned int*)&vv)[j] = ((unsigned)s << 8) | (unsigned)(d & 255);
          ((unsigned short*)&bb4)[j] = (unsigned short)bkt;
          atomicAdd(&cnt[bkt], 1);
        } else {
          ((unsigned int*)&vv)[j] = 0xFFFFFFFFu;
          ((unsigned short*)&bb4)[j] = 0xFFFFu;
        }
      }
    }
    *(uint4*)(raw + slot) = vv;
    *(ushort4*)(rawB + slot) = bb4;
  }
  __syncthreads();
  for (int b = tid; b < NB; b += 256){
    int rr = cnt[b];
    int pr = (rr + 15) & ~15;          // 16-entry (64B) aligned reservation
    int bs = atomicAdd(&gTail[b], pr);
    base[b] = bs;
    if (rr) atomicAdd(&gReal[b], rr);
    unsigned int* dp = binned + (size_t)b * CAPB;
    for (int k2 = rr; k2 < pr; ++k2){
      int p = bs + k2;
      if (p < CAPB) dp[p] = 0xFFFFFFFFu;   // sentinel
    }
  }
  __syncthreads();
  for (int r = 0; r < 16; ++r){
    int slot = r * 1024 + tid * 4;
    uint4 vv = *(const uint4*)(raw + slot);
    ushort4 bb4 = *(const ushort4*)(rawB + slot);
    #pragma unroll
    for (int j = 0; j < 4; j++){
      unsigned short bkt = ((unsigned short*)&bb4)[j];
      if (bkt != 0xFFFFu){
        int p = base[bkt] + atomicAdd(&cnt2[bkt], 1);
        if (p < CAPB) binned[(size_t)bkt * CAPB + p] = ((unsigned int*)&vv)[j];
      }
    }
  }
}

// ---- Phase B: per-bucket LDS counting sort -> coalesced csrSrc/deg/rowStart.
// Bucket base computed inline (each block scans the 391 counts, ~2us). ----
__global__ __launch_bounds__(256) void k_sort(const unsigned int* __restrict__ binned,
    const int* __restrict__ gTail, const int* __restrict__ gReal,
    int* __restrict__ deg, int* __restrict__ rowStart, int* __restrict__ csrSrc){
  __shared__ int sg[512];
  __shared__ int cnt[256], excl[256], cur[256];
  __shared__ int sorted[SCAP];
  int b = blockIdx.x, tid = threadIdx.x;
  // inline exclusive prefix over gReal[0..NB)
  int v0 = tid < NB ? gReal[tid] : 0;
  int v1 = (tid + 256) < NB ? gReal[tid + 256] : 0;
  sg[tid] = v0; sg[tid + 256] = v1;
  cnt[tid] = 0;
  __syncthreads();
  for (int o = 1; o < 512; o <<= 1){
    int t0 = (tid >= o) ? sg[tid - o] : 0;
    int t1 = (tid + 256 >= o) ? sg[tid + 256 - o] : 0;
    __syncthreads();
    sg[tid] += t0; sg[tid + 256] += t1;
    __syncthreads();
  }
  int base = (b == 0) ? 0 : sg[b - 1];   // exclusive prefix at b
  int n = gTail[b]; if (n > CAPB) n = CAPB;
  const unsigned int* L = binned + (size_t)b * CAPB;
  for (int i = tid; i < n; i += 256){
    unsigned int v = __builtin_nontemporal_load(L + i);
    if ((v >> 8) < NN) atomicAdd(&cnt[v & 255], 1);
  }
  __syncthreads();
  int myc = cnt[tid];
  excl[tid] = myc;
  __syncthreads();
  for (int o = 1; o < 256; o <<= 1){
    int t = (tid >= o) ? excl[tid - o] : 0;
    __syncthreads();
    excl[tid] += t;
    __syncthreads();
  }
  int ex = excl[tid] - myc;
  int node = b * 256 + tid;
  if (node < NN){ deg[node] = myc; rowStart[node] = base + ex; }
  cur[tid] = ex;
  __syncthreads();
  int m = excl[255];
  for (int i = tid; i < n; i += 256){
    unsigned int v = __builtin_nontemporal_load(L + i);
    unsigned int s = v >> 8;
    if (s < NN){
      int p = atomicAdd(&cur[v & 255], 1);
      if (p < SCAP) sorted[p] = (int)s;
    }
  }
  __syncthreads();
  for (int i = tid; i < m; i += 256)
    __builtin_nontemporal_store(sorted[i], csrSrc + base + i);
}

// ---- fused aggregation, single full-row pass: one wave per dst node.
// uint2 (8B/lane) gather; bf16->f32 via shift/mask (2 VALU for 2 feats). ----
__global__ __launch_bounds__(256) void k_agg(const int* __restrict__ csrSrc,
    const int* __restrict__ rowStart, const int* __restrict__ deg,
    const float* __restrict__ q, const float* __restrict__ kv,
    const unsigned short* __restrict__ h, float* __restrict__ outp){
  int w = (blockIdx.x * 256 + threadIdx.x) >> 6;
  int lane = threadIdx.x & 63;
  int start = rowStart[w], d = deg[w];
  float kd = kv[w];
  float a0 = 0.f, a1 = 0.f, a2 = 0.f, a3 = 0.f, ssum = 0.f;
  for (int bse = 0; bse < d; bse += 64){
    int cnt = min(64, d - bse);
    float ex = 0.f; int s = 0;
    if (lane < cnt){
      s = __builtin_nontemporal_load(csrSrc + start + bse + lane);
      float c = q[s] + kd;
      c = c > 0.f ? c : 0.2f * c;
      ex = __expf(c);
    }
    ssum += ex;
    for (int j0 = 0; j0 < cnt; j0 += 8){
      float wg[8]; uint2 hv[8];
      #pragma unroll
      for (int jj = 0; jj < 8; jj++){
        int j = j0 + jj;                 // j >= cnt: ex=0, s=0 -> wg 0, row 0 (hot)
        wg[jj] = __shfl(ex, j, 64);
        int sj = __shfl(s, j, 64);
        hv[jj] = *(const uint2*)(h + (size_t)sj * 256 + lane * 4);
      }
      #pragma unroll
      for (int jj = 0; jj < 8; jj++){
        unsigned int u0 = hv[jj].x, u1 = hv[jj].y;
        a0 += wg[jj] * __uint_as_float(u0 << 16);
        a1 += wg[jj] * __uint_as_float(u0 & 0xFFFF0000u);
        a2 += wg[jj] * __uint_as_float(u1 << 16);
        a3 += wg[jj] * __uint_as_float(u1 & 0xFFFF0000u);
      }
    }
  }
  #pragma unroll
  for (int o = 32; o; o >>= 1) ssum += __shfl_xor(ssum, o, 64);
  float inv = d > 0 ? 1.0f / ssum : 0.0f;
  f32x4 r; r[0] = a0 * inv; r[1] = a1 * inv; r[2] = a2 * inv; r[3] = a3 * inv;
  __builtin_nontemporal_store(r, (f32x4*)(outp + (size_t)w * 256 + lane * 4));
}

extern "C" void kernel_launch(void* const* d_in, const int* in_sizes, int n_in,
                              void* d_out, int out_size, void* d_ws, size_t ws_size,
                              hipStream_t stream){
  const float* x  = (const float*)d_in[0];
  const float* Wv = (const float*)d_in[1];
  const float* bv = (const float*)d_in[2];
  const float* wq = (const float*)d_in[3];
  const float* bq = (const float*)d_in[4];
  const float* wk = (const float*)d_in[5];
  const float* bk = (const float*)d_in[6];
  const int*   src = (const int*)d_in[7];
  const int*   dst = (const int*)d_in[8];
  float* out = (float*)d_out;

  char* ws = (char*)d_ws;
  size_t off = 0;
  auto alloc = [&](size_t bytes) -> char* {
    off = (off + 511) & ~(size_t)511;
    char* p = ws + off; off += bytes; return p;
  };
  unsigned short* h  = (unsigned short*)alloc((size_t)NPAD * 256 * 2);  // 51.25MB [NPAD][256]
  unsigned short* xs = (unsigned short*)alloc((size_t)NPAD * 256 * 2);  // 51.25MB
  // xs dead after k_gemm; binned (19.2MB) + csrSrc (12.8MB) alias it (32MB <= 51.25MB)
  unsigned int* binned = (unsigned int*)xs;
  int* csrSrc = (int*)((char*)xs + (size_t)NB * CAPB * 4);
  unsigned short* wvt  = (unsigned short*)alloc(256 * 256 * 2);
  float* vq     = (float*)alloc(256 * 4);
  float* vk     = (float*)alloc(256 * 4);
  float* consts = (float*)alloc(512);
  float* q      = (float*)alloc((size_t)NN * 4);
  float* kv     = (float*)alloc((size_t)NN * 4);
  int* deg      = (int*)alloc((size_t)NN * 4);
  int* rowStart = (int*)alloc((size_t)NN * 4);
  int* gTail    = (int*)alloc((size_t)NB * 4 * 2);   // gTail + gReal contiguous
  int* gReal    = gTail + NB;

  (void)hipMemsetAsync(gTail, 0, (size_t)NB * 4 * 2, stream);
  k_prep<<<512, 256, 0, stream>>>(Wv, bv, wq, bq, wk, bk, wvt, vq, vk, consts);
  k_convert_qk<<<NN / 4, 256, 0, stream>>>(x, vq, vk, consts, xs, q, kv);
  k_gemm<<<(NPAD / 128) * 2, 256, 0, stream>>>(xs, wvt, bv, h);
  k_group<<<GBLK, 256, 0, stream>>>(src, dst, gTail, gReal, binned);
  k_sort<<<NB, 256, 0, stream>>>(binned, gTail, gReal, deg, rowStart, csrSrc);
  k_agg<<<NN / 4, 256, 0, stream>>>(csrSrc, rowStart, deg, q, kv, h, out);
}